// Round 2
// baseline (573.800 us; speedup 1.0000x reference)
//
#include <hip/hip_runtime.h>
#include <hip/hip_bf16.h>

// AUGRU (DIEN) fused recurrent kernel. fp32 I/O, bf16 MFMA compute.
// B=2048, T=200, D=H=128. Block = 8 batch rows (256 blocks, 1/CU), 512 thr.
// Round 5: resubmission of Round 4 (two consecutive GPU-acquisition timeouts,
// no measurement yet). Changes under test vs the 593.1 us baseline:
//   - LDS-only barriers (no vmcnt drain -> x-prefetch + OUT stores stay in
//     flight across steps)
//   - x A-frags cached in registers across gate->cand
//   - cand GEMM split into 4 depth-2 MFMA chains

#define BB   2048
#define TT   200
#define DD   128
#define HH   128
#define NG   256
#define BM   8
#define SB   136     // bf16 tile row stride (shorts): 68 dwords = 4 mod 32
#define SF   132     // fp32 row stride (floats)
#define NTH  512

typedef __attribute__((ext_vector_type(8))) __bf16 bf16x8;
typedef __attribute__((ext_vector_type(4))) float  f32x4;

#define MFMA(a, b, c) __builtin_amdgcn_mfma_f32_16x16x32_bf16((a), (b), (c), 0, 0, 0)

union bfu { __bf16 b; unsigned short u; };
__device__ __forceinline__ unsigned short f2bf(float f) { bfu c; c.b = (__bf16)f; return c.u; }
__device__ __forceinline__ __bf16 f2bfv(float f) { return (__bf16)f; }

// Barrier with LDS-ordering only. __syncthreads() would emit
// s_waitcnt vmcnt(0) lgkmcnt(0) and drain the x-prefetch (HBM latency!) and
// the OUT stores every step. Cross-wave ordering here is LDS-only, so
// lgkmcnt(0) + s_barrier is sufficient (m139/m201 pattern).
__device__ __forceinline__ void lds_barrier() {
    __builtin_amdgcn_sched_barrier(0);
    asm volatile("s_waitcnt lgkmcnt(0)" ::: "memory");
    __builtin_amdgcn_s_barrier();
    __builtin_amdgcn_sched_barrier(0);
}

__global__ __launch_bounds__(NTH, 2)
void augru_kernel(const float* __restrict__ X,    // [B,T,D]
                  const float* __restrict__ ATT,  // [B,T]
                  const int*   __restrict__ SL,   // [B]
                  const float* __restrict__ WG,   // [256,256]
                  const float* __restrict__ BG,   // [256]
                  const float* __restrict__ WC,   // [256,128]
                  const float* __restrict__ BC,   // [128]
                  float*       __restrict__ OUT)  // [B,T,H]
{
    __shared__ unsigned short xb[2][16 * SB];  // x_t double buffer, bf16, rows 8..15 = 0
    __shared__ unsigned short hb[16 * SB];     // h bf16 (A-frag source), rows 8..15 = 0
    __shared__ unsigned short rh[16 * SB];     // r*h bf16, rows 8..15 = 0
    __shared__ float hs[BM * SF];              // fp32 h master
    __shared__ float ub[BM * SF];              // a_t * sigmoid(u)
    __shared__ float attall[BM * TT];
    __shared__ int   slbuf[BM];

    const int tid  = threadIdx.x;
    const int wave = tid >> 6;
    const int lane = tid & 63;
    const int quad = lane >> 4;
    const int l16  = lane & 15;
    const int b0   = blockIdx.x * BM;
    const int qq   = quad & 1;       // row-group select after redistribution
    const int top  = quad >> 1;
    const int r0   = 4 * qq + 2 * top;   // this lane handles rows r0, r0+1

    // ---------------- one-time init ----------------
    for (int i = tid; i < 2 * 16 * SB; i += NTH) xb[0][i] = 0;   // both buffers
    for (int i = tid; i < 16 * SB; i += NTH) hb[i] = 0;
    for (int i = tid; i < 16 * SB; i += NTH) rh[i] = 0;
    for (int i = tid; i < BM * SF; i += NTH) { hs[i] = 0.f; ub[i] = 0.f; }
    for (int i = tid; i < BM * TT; i += NTH) attall[i] = ATT[(long)b0 * TT + i];
    if (tid < BM) slbuf[tid] = SL[b0 + tid];

    // per-lane biases (fixed columns per lane across all steps)
    const float bgv0 = BG[(2 * wave) * 16 + l16];
    const float bgv1 = BG[(2 * wave + 1) * 16 + l16];
    const float bcv  = BC[wave * 16 + l16];

    // Weight B-fragments (bf16) in registers.
    // B-frag (16x16x32): lane holds B[k = kk*32 + quad*8 + j][n = ntile*16 + l16]
    bf16x8 bgf[2][8], bcf[8];
    {
        const int nc0 = (2 * wave) * 16 + l16;
        const int nc1 = nc0 + 16;
        const int ncc = wave * 16 + l16;
        #pragma unroll
        for (int kk = 0; kk < 8; ++kk) {
            bf16x8 t0, t1, t2;
            #pragma unroll
            for (int j = 0; j < 8; ++j) {
                const int k = kk * 32 + quad * 8 + j;
                t0[j] = f2bfv(WG[k * NG + nc0]);
                t1[j] = f2bfv(WG[k * NG + nc1]);
                t2[j] = f2bfv(WC[k * HH + ncc]);
            }
            bgf[0][kk] = t0; bgf[1][kk] = t1; bcf[kk] = t2;
        }
    }
    __syncthreads();   // full barrier once (init loads must land)

    int tmax = 0;
    #pragma unroll
    for (int r = 0; r < BM; ++r) tmax = max(tmax, slbuf[r]);
    const int sl0 = slbuf[r0], sl1 = slbuf[r0 + 1];

    const int srow = tid >> 5;   // 0..7 for tid<256
    const int sseg = tid & 31;

    // prologue: stage x(0), prefetch x(1)
    float4 xpre;
    if (tid < 256 && tmax > 0) {
        xpre = *(const float4*)&X[((long)(b0 + srow) * TT + 0) * DD + sseg * 4];
        ushort4 v; v.x = f2bf(xpre.x); v.y = f2bf(xpre.y); v.z = f2bf(xpre.z); v.w = f2bf(xpre.w);
        *(ushort4*)&xb[0][srow * SB + sseg * 4] = v;
        if (tmax > 1)
            xpre = *(const float4*)&X[((long)(b0 + srow) * TT + 1) * DD + sseg * 4];
    }
    lds_barrier();   // SYNC A for t=0 (x(1) prefetch stays in flight)

    // ---------------- time loop ----------------
    for (int t = 0; t < tmax; ++t) {
        const unsigned short* xc = &xb[t & 1][0];

        // x A-fragments: loaded once, reused by both GEMMs this step
        bf16x8 afx[4];
        #pragma unroll
        for (int kk = 0; kk < 4; ++kk)
            afx[kk] = *(const bf16x8*)&xc[l16 * SB + kk * 32 + quad * 8];

        // ---- gate GEMM: [x|h] @ Wg, 4 independent MFMA chains ----
        f32x4 a0 = {0.f,0.f,0.f,0.f}, a1 = {0.f,0.f,0.f,0.f};
        f32x4 a2 = {0.f,0.f,0.f,0.f}, a3 = {0.f,0.f,0.f,0.f};
        a0 = MFMA(afx[0], bgf[0][0], a0); a1 = MFMA(afx[0], bgf[1][0], a1);
        a2 = MFMA(afx[1], bgf[0][1], a2); a3 = MFMA(afx[1], bgf[1][1], a3);
        a0 = MFMA(afx[2], bgf[0][2], a0); a1 = MFMA(afx[2], bgf[1][2], a1);
        a2 = MFMA(afx[3], bgf[0][3], a2); a3 = MFMA(afx[3], bgf[1][3], a3);
        #pragma unroll
        for (int kk = 4; kk < 8; kk += 2) {
            const bf16x8 af0 = *(const bf16x8*)&hb[l16 * SB + (kk - 4) * 32 + quad * 8];
            const bf16x8 af1 = *(const bf16x8*)&hb[l16 * SB + (kk - 3) * 32 + quad * 8];
            a0 = MFMA(af0, bgf[0][kk], a0);     a1 = MFMA(af0, bgf[1][kk], a1);
            a2 = MFMA(af1, bgf[0][kk + 1], a2); a3 = MFMA(af1, bgf[1][kk + 1], a3);
        }

        // stage x(t+1) into the other buffer; then prefetch x(t+2)
        if (tid < 256 && t + 1 < tmax) {
            ushort4 v; v.x = f2bf(xpre.x); v.y = f2bf(xpre.y); v.z = f2bf(xpre.z); v.w = f2bf(xpre.w);
            *(ushort4*)&xb[(t + 1) & 1][srow * SB + sseg * 4] = v;
            if (t + 2 < tmax)
                xpre = *(const float4*)&X[((long)(b0 + srow) * TT + (t + 2)) * DD + sseg * 4];
        }

        // ---- gate epilogue (full-lane via xor-32 redistribution) ----
        const f32x4 g0 = a0 + a2;   // ntile 0
        const f32x4 g1 = a1 + a3;   // ntile 1
        float s20 = __shfl_xor(g0[2], 32, 64), s30 = __shfl_xor(g0[3], 32, 64);
        float s21 = __shfl_xor(g1[2], 32, 64), s31 = __shfl_xor(g1[3], 32, 64);
        #pragma unroll
        for (int nt = 0; nt < 2; ++nt) {
            const int colg = (2 * wave + nt) * 16 + l16;
            const float bg = nt ? bgv1 : bgv0;
            const float v0 = top ? (nt ? s21 : s20) : (nt ? g1[0] : g0[0]);
            const float v1 = top ? (nt ? s31 : s30) : (nt ? g1[1] : g0[1]);
            #pragma unroll
            for (int rr = 0; rr < 2; ++rr) {
                const int row = r0 + rr;
                const float pre = (rr ? v1 : v0) + bg;
                const float s = __builtin_amdgcn_rcpf(1.0f + __expf(-pre));
                if (wave < 4) {
                    rh[row * SB + colg] = f2bf(s * hs[row * SF + colg]);
                } else {
                    ub[row * SF + (colg - HH)] = attall[row * TT + t] * s;
                }
            }
        }
        lds_barrier();   // SYNC B: rh, ub ready (x(t+2) prefetch stays in flight)

        // ---- cand GEMM: [x | r*h] @ Wc, 4 independent depth-2 chains ----
        f32x4 c0 = {0.f,0.f,0.f,0.f}, c1 = {0.f,0.f,0.f,0.f};
        f32x4 c2 = {0.f,0.f,0.f,0.f}, c3 = {0.f,0.f,0.f,0.f};
        {
            const bf16x8 afr0 = *(const bf16x8*)&rh[l16 * SB + 0 * 32 + quad * 8];
            const bf16x8 afr1 = *(const bf16x8*)&rh[l16 * SB + 1 * 32 + quad * 8];
            const bf16x8 afr2 = *(const bf16x8*)&rh[l16 * SB + 2 * 32 + quad * 8];
            const bf16x8 afr3 = *(const bf16x8*)&rh[l16 * SB + 3 * 32 + quad * 8];
            c0 = MFMA(afx[0], bcf[0], c0); c1 = MFMA(afr0, bcf[4], c1);
            c2 = MFMA(afx[1], bcf[1], c2); c3 = MFMA(afr1, bcf[5], c3);
            c0 = MFMA(afx[2], bcf[2], c0); c1 = MFMA(afr2, bcf[6], c1);
            c2 = MFMA(afx[3], bcf[3], c2); c3 = MFMA(afr3, bcf[7], c3);
        }
        const f32x4 cc = (c0 + c2) + (c1 + c3);
        float t2 = __shfl_xor(cc[2], 32, 64), t3 = __shfl_xor(cc[3], 32, 64);

        // ---- update epilogue (full-lane) ----
        {
            const int col = wave * 16 + l16;
            const float w0 = top ? t2 : cc[0];
            const float w1 = top ? t3 : cc[1];
            #pragma unroll
            for (int rr = 0; rr < 2; ++rr) {
                const int row = r0 + rr;
                const float xv = (rr ? w1 : w0) + bcv;
                const float e  = __expf(2.0f * xv);
                const float c  = 1.0f - 2.0f * __builtin_amdgcn_rcpf(e + 1.0f);
                const float u  = ub[row * SF + col];
                const float ho = hs[row * SF + col];
                const float nh = fmaf(u, c - ho, ho);
                const bool valid = t < (rr ? sl1 : sl0);
                const float hst = valid ? nh : ho;
                hs[row * SF + col] = hst;
                hb[row * SB + col] = f2bf(hst);
                OUT[((long)(b0 + row) * TT + t) * HH + col] = valid ? nh : 0.f;
            }
        }
        lds_barrier();   // SYNC A for t+1: h (and staged x) ready; OUT stores stay in flight
    }

    // tail: outputs for t in [tmax, TT) are zeros
    const int n4 = (TT - tmax) * (HH / 4);
    for (int r = 0; r < BM; ++r) {
        float4* p = (float4*)(OUT + ((long)(b0 + r) * TT + tmax) * HH);
        for (int i = tid; i < n4; i += NTH) p[i] = make_float4(0.f, 0.f, 0.f, 0.f);
    }
}

extern "C" void kernel_launch(void* const* d_in, const int* in_sizes, int n_in,
                              void* d_out, int out_size, void* d_ws, size_t ws_size,
                              hipStream_t stream) {
    (void)in_sizes; (void)n_in; (void)d_ws; (void)ws_size; (void)out_size;
    const float* X   = (const float*)d_in[0];
    const float* ATT = (const float*)d_in[1];
    const int*   SL  = (const int*)d_in[2];
    const float* WG  = (const float*)d_in[3];
    const float* BG  = (const float*)d_in[4];
    const float* WC  = (const float*)d_in[5];
    const float* BC  = (const float*)d_in[6];
    float*       OUT = (float*)d_out;
    hipLaunchKernelGGL(augru_kernel, dim3(BB / BM), dim3(NTH), 0, stream,
                       X, ATT, SL, WG, BG, WC, BC, OUT);
}

// Round 6
// 501.110 us; speedup vs baseline: 1.1451x; 1.1451x over previous
//
#include <hip/hip_runtime.h>
#include <hip/hip_bf16.h>

// AUGRU (DIEN) fused recurrent kernel. fp32 I/O, bf16 MFMA compute.
// B=2048, T=200, D=H=128. Block = 8 batch rows (256 blocks, 1/CU), 256 thr.
// Round 9: byte-identical resubmission of Round 8 (GPU-acquisition timeout).
// 4-wave restructure: each wave owns cand cols 32w..32w+31 (2 ntiles) and
// gate ntiles {2w,2w+1} (r) + {2w+8,2w+9} (u), so the identical A-fragments
// are read by 4 waves instead of 8 -> LDS-pipe load for A-frags halves
// (48 ds_read_b128/step vs 96). Same total MFMA count (4x48 vs 8x24).
// h (fp32) and att*u live in registers per thread (2 rows x 2 cols each);
// hs/ub LDS buffers deleted. LDS-only barriers (no vmcnt drain) from R4.

#define BB   2048
#define TT   200
#define DD   128
#define HH   128
#define NG   256
#define BM   8
#define SB   136     // bf16 tile row stride (shorts): 68 dwords = 4 mod 32
#define NTH  256

typedef __attribute__((ext_vector_type(8))) __bf16 bf16x8;
typedef __attribute__((ext_vector_type(4))) float  f32x4;

#define MFMA(a, b, c) __builtin_amdgcn_mfma_f32_16x16x32_bf16((a), (b), (c), 0, 0, 0)

union bfu { __bf16 b; unsigned short u; };
__device__ __forceinline__ unsigned short f2bf(float f) { bfu c; c.b = (__bf16)f; return c.u; }
__device__ __forceinline__ __bf16 f2bfv(float f) { return (__bf16)f; }
__device__ __forceinline__ float sigm(float x) { return __builtin_amdgcn_rcpf(1.0f + __expf(-x)); }

// Barrier with LDS-ordering only (no vmcnt drain; x-prefetch + OUT stores
// stay in flight across steps). Cross-wave ordering here is LDS-only.
__device__ __forceinline__ void lds_barrier() {
    __builtin_amdgcn_sched_barrier(0);
    asm volatile("s_waitcnt lgkmcnt(0)" ::: "memory");
    __builtin_amdgcn_s_barrier();
    __builtin_amdgcn_sched_barrier(0);
}

__global__ __launch_bounds__(NTH, 1)
void augru_kernel(const float* __restrict__ X,    // [B,T,D]
                  const float* __restrict__ ATT,  // [B,T]
                  const int*   __restrict__ SL,   // [B]
                  const float* __restrict__ WG,   // [256,256]
                  const float* __restrict__ BG,   // [256]
                  const float* __restrict__ WC,   // [256,128]
                  const float* __restrict__ BC,   // [128]
                  float*       __restrict__ OUT)  // [B,T,H]
{
    __shared__ unsigned short xb[2][16 * SB];  // x_t double buffer, bf16, rows 8..15 = 0
    __shared__ unsigned short hb[16 * SB];     // h bf16 (A-frag source), rows 8..15 = 0
    __shared__ unsigned short rh[16 * SB];     // r*h bf16, rows 8..15 = 0
    __shared__ float attall[BM * TT];
    __shared__ int   slbuf[BM];

    const int tid  = threadIdx.x;
    const int wave = tid >> 6;       // 0..3
    const int lane = tid & 63;
    const int quad = lane >> 4;
    const int l16  = lane & 15;
    const int b0   = blockIdx.x * BM;
    const int qq   = quad & 1;       // row-group select after redistribution
    const int top  = quad >> 1;
    const int r0   = 4 * qq + 2 * top;   // this lane handles rows r0, r0+1

    // ---------------- one-time init ----------------
    for (int i = tid; i < 2 * 16 * SB; i += NTH) xb[0][i] = 0;   // both buffers
    for (int i = tid; i < 16 * SB; i += NTH) hb[i] = 0;
    for (int i = tid; i < 16 * SB; i += NTH) rh[i] = 0;
    for (int i = tid; i < BM * TT; i += NTH) attall[i] = ATT[(long)b0 * TT + i];
    if (tid < BM) slbuf[tid] = SL[b0 + tid];

    // Columns this thread owns (cand / r-gate / h / out): c0, c1 = c0+16.
    // u-gate cols: c0+128, c1+128.
    const int c0 = wave * 32 + l16;
    const int c1 = c0 + 16;
    const float bgr0 = BG[c0],      bgr1 = BG[c1];        // r-gate biases
    const float bgu0 = BG[c0 + HH], bgu1 = BG[c1 + HH];   // u-gate biases
    const float bc0v = BC[c0],      bc1v = BC[c1];        // cand biases

    // Weight B-fragments (bf16) in registers.
    // B-frag (16x16x32): lane holds B[k = kk*32 + quad*8 + j][col]
    // bgf[0]:WG col c0 (r), bgf[1]:WG col c1 (r),
    // bgf[2]:WG col c0+128 (u), bgf[3]:WG col c1+128 (u),
    // bcf[0]:WC col c0, bcf[1]:WC col c1.
    bf16x8 bgf[4][8], bcf[2][8];
    {
        #pragma unroll
        for (int kk = 0; kk < 8; ++kk) {
            bf16x8 t0, t1, t2, t3, t4, t5;
            #pragma unroll
            for (int j = 0; j < 8; ++j) {
                const int k = kk * 32 + quad * 8 + j;
                t0[j] = f2bfv(WG[k * NG + c0]);
                t1[j] = f2bfv(WG[k * NG + c1]);
                t2[j] = f2bfv(WG[k * NG + c0 + HH]);
                t3[j] = f2bfv(WG[k * NG + c1 + HH]);
                t4[j] = f2bfv(WC[k * HH + c0]);
                t5[j] = f2bfv(WC[k * HH + c1]);
            }
            bgf[0][kk] = t0; bgf[1][kk] = t1; bgf[2][kk] = t2; bgf[3][kk] = t3;
            bcf[0][kk] = t4; bcf[1][kk] = t5;
        }
    }
    __syncthreads();   // full barrier once (init loads must land)

    int tmax = 0;
    #pragma unroll
    for (int r = 0; r < BM; ++r) tmax = max(tmax, slbuf[r]);
    const int sl0 = slbuf[r0], sl1 = slbuf[r0 + 1];

    // Persistent per-thread state: h (fp32) for (rows r0,r0+1) x (cols c0,c1).
    float h00 = 0.f, h01 = 0.f, h10 = 0.f, h11 = 0.f;   // hXY: X=row, Y=col

    const int srow = tid >> 5;   // 0..7
    const int sseg = tid & 31;

    // prologue: stage x(0), prefetch x(1)
    float4 xpre;
    if (tmax > 0) {
        xpre = *(const float4*)&X[((long)(b0 + srow) * TT + 0) * DD + sseg * 4];
        ushort4 v; v.x = f2bf(xpre.x); v.y = f2bf(xpre.y); v.z = f2bf(xpre.z); v.w = f2bf(xpre.w);
        *(ushort4*)&xb[0][srow * SB + sseg * 4] = v;
        if (tmax > 1)
            xpre = *(const float4*)&X[((long)(b0 + srow) * TT + 1) * DD + sseg * 4];
    }
    lds_barrier();   // SYNC A for t=0 (x(1) prefetch stays in flight)

    // ---------------- time loop ----------------
    for (int t = 0; t < tmax; ++t) {
        const unsigned short* xc = &xb[t & 1][0];

        // x A-fragments: loaded once, reused by both GEMMs this step.
        bf16x8 afx[4];
        #pragma unroll
        for (int kk = 0; kk < 4; ++kk)
            afx[kk] = *(const bf16x8*)&xc[l16 * SB + kk * 32 + quad * 8];

        // attention scores for this step (latency hides under gate MFMAs)
        const float at0 = attall[r0 * TT + t];
        const float at1 = attall[(r0 + 1) * TT + t];

        // ---- gate GEMM: [x|h] @ Wg, 8 independent MFMA chains ----
        // chains: a{0,1}=nt c0(r), a{2,3}=nt c1(r), a{4,5}=nt c0+128(u), a{6,7}=nt c1+128(u)
        f32x4 a0 = {0.f,0.f,0.f,0.f}, a1 = {0.f,0.f,0.f,0.f};
        f32x4 a2 = {0.f,0.f,0.f,0.f}, a3 = {0.f,0.f,0.f,0.f};
        f32x4 a4 = {0.f,0.f,0.f,0.f}, a5 = {0.f,0.f,0.f,0.f};
        f32x4 a6 = {0.f,0.f,0.f,0.f}, a7 = {0.f,0.f,0.f,0.f};
        // x part (kk = 0..3)
        a0 = MFMA(afx[0], bgf[0][0], a0); a2 = MFMA(afx[0], bgf[1][0], a2);
        a4 = MFMA(afx[0], bgf[2][0], a4); a6 = MFMA(afx[0], bgf[3][0], a6);
        a1 = MFMA(afx[1], bgf[0][1], a1); a3 = MFMA(afx[1], bgf[1][1], a3);
        a5 = MFMA(afx[1], bgf[2][1], a5); a7 = MFMA(afx[1], bgf[3][1], a7);
        a0 = MFMA(afx[2], bgf[0][2], a0); a2 = MFMA(afx[2], bgf[1][2], a2);
        a4 = MFMA(afx[2], bgf[2][2], a4); a6 = MFMA(afx[2], bgf[3][2], a6);
        a1 = MFMA(afx[3], bgf[0][3], a1); a3 = MFMA(afx[3], bgf[1][3], a3);
        a5 = MFMA(afx[3], bgf[2][3], a5); a7 = MFMA(afx[3], bgf[3][3], a7);
        // h part (kk = 4..7)
        {
            const bf16x8 afh0 = *(const bf16x8*)&hb[l16 * SB + 0 * 32 + quad * 8];
            const bf16x8 afh1 = *(const bf16x8*)&hb[l16 * SB + 1 * 32 + quad * 8];
            const bf16x8 afh2 = *(const bf16x8*)&hb[l16 * SB + 2 * 32 + quad * 8];
            const bf16x8 afh3 = *(const bf16x8*)&hb[l16 * SB + 3 * 32 + quad * 8];
            a0 = MFMA(afh0, bgf[0][4], a0); a2 = MFMA(afh0, bgf[1][4], a2);
            a4 = MFMA(afh0, bgf[2][4], a4); a6 = MFMA(afh0, bgf[3][4], a6);
            a1 = MFMA(afh1, bgf[0][5], a1); a3 = MFMA(afh1, bgf[1][5], a3);
            a5 = MFMA(afh1, bgf[2][5], a5); a7 = MFMA(afh1, bgf[3][5], a7);
            a0 = MFMA(afh2, bgf[0][6], a0); a2 = MFMA(afh2, bgf[1][6], a2);
            a4 = MFMA(afh2, bgf[2][6], a4); a6 = MFMA(afh2, bgf[3][6], a6);
            a1 = MFMA(afh3, bgf[0][7], a1); a3 = MFMA(afh3, bgf[1][7], a3);
            a5 = MFMA(afh3, bgf[2][7], a5); a7 = MFMA(afh3, bgf[3][7], a7);
        }

        // stage x(t+1) into the other buffer; then prefetch x(t+2)
        if (t + 1 < tmax) {
            ushort4 v; v.x = f2bf(xpre.x); v.y = f2bf(xpre.y); v.z = f2bf(xpre.z); v.w = f2bf(xpre.w);
            *(ushort4*)&xb[(t + 1) & 1][srow * SB + sseg * 4] = v;
            if (t + 2 < tmax)
                xpre = *(const float4*)&X[((long)(b0 + srow) * TT + (t + 2)) * DD + sseg * 4];
        }

        // ---- gate epilogue (full-lane via xor-32 redistribution) ----
        const f32x4 gr0 = a0 + a1;   // r-gate, col c0
        const f32x4 gr1 = a2 + a3;   // r-gate, col c1
        const f32x4 gu0 = a4 + a5;   // u-gate, col c0+128
        const f32x4 gu1 = a6 + a7;   // u-gate, col c1+128
        const float r02 = __shfl_xor(gr0[2], 32, 64), r03 = __shfl_xor(gr0[3], 32, 64);
        const float r12 = __shfl_xor(gr1[2], 32, 64), r13 = __shfl_xor(gr1[3], 32, 64);
        const float u02 = __shfl_xor(gu0[2], 32, 64), u03 = __shfl_xor(gu0[3], 32, 64);
        const float u12 = __shfl_xor(gu1[2], 32, 64), u13 = __shfl_xor(gu1[3], 32, 64);
        float ug00, ug01, ug10, ug11;   // att * sigmoid(u), [row][col]
        {
            // col c0
            const float rs00 = sigm((top ? r02 : gr0[0]) + bgr0);   // row r0
            const float rs10 = sigm((top ? r03 : gr0[1]) + bgr0);   // row r0+1
            rh[r0 * SB + c0]       = f2bf(rs00 * h00);
            rh[(r0 + 1) * SB + c0] = f2bf(rs10 * h10);
            ug00 = at0 * sigm((top ? u02 : gu0[0]) + bgu0);
            ug10 = at1 * sigm((top ? u03 : gu0[1]) + bgu0);
            // col c1
            const float rs01 = sigm((top ? r12 : gr1[0]) + bgr1);
            const float rs11 = sigm((top ? r13 : gr1[1]) + bgr1);
            rh[r0 * SB + c1]       = f2bf(rs01 * h01);
            rh[(r0 + 1) * SB + c1] = f2bf(rs11 * h11);
            ug01 = at0 * sigm((top ? u12 : gu1[0]) + bgu1);
            ug11 = at1 * sigm((top ? u13 : gu1[1]) + bgu1);
        }
        lds_barrier();   // SYNC B: rh ready (x(t+2) prefetch stays in flight)

        // ---- cand GEMM: [x | r*h] @ Wc, 4 independent depth-4 chains ----
        f32x4 q0 = {0.f,0.f,0.f,0.f}, q1 = {0.f,0.f,0.f,0.f};
        f32x4 q2 = {0.f,0.f,0.f,0.f}, q3 = {0.f,0.f,0.f,0.f};
        {
            const bf16x8 afr0 = *(const bf16x8*)&rh[l16 * SB + 0 * 32 + quad * 8];
            const bf16x8 afr1 = *(const bf16x8*)&rh[l16 * SB + 1 * 32 + quad * 8];
            const bf16x8 afr2 = *(const bf16x8*)&rh[l16 * SB + 2 * 32 + quad * 8];
            const bf16x8 afr3 = *(const bf16x8*)&rh[l16 * SB + 3 * 32 + quad * 8];
            q0 = MFMA(afx[0], bcf[0][0], q0); q2 = MFMA(afx[0], bcf[1][0], q2);
            q1 = MFMA(afx[1], bcf[0][1], q1); q3 = MFMA(afx[1], bcf[1][1], q3);
            q0 = MFMA(afx[2], bcf[0][2], q0); q2 = MFMA(afx[2], bcf[1][2], q2);
            q1 = MFMA(afx[3], bcf[0][3], q1); q3 = MFMA(afx[3], bcf[1][3], q3);
            q0 = MFMA(afr0, bcf[0][4], q0);   q2 = MFMA(afr0, bcf[1][4], q2);
            q1 = MFMA(afr1, bcf[0][5], q1);   q3 = MFMA(afr1, bcf[1][5], q3);
            q0 = MFMA(afr2, bcf[0][6], q0);   q2 = MFMA(afr2, bcf[1][6], q2);
            q1 = MFMA(afr3, bcf[0][7], q1);   q3 = MFMA(afr3, bcf[1][7], q3);
        }
        const f32x4 cc0 = q0 + q1;   // col c0
        const f32x4 cc1 = q2 + q3;   // col c1
        const float c02 = __shfl_xor(cc0[2], 32, 64), c03 = __shfl_xor(cc0[3], 32, 64);
        const float c12 = __shfl_xor(cc1[2], 32, 64), c13 = __shfl_xor(cc1[3], 32, 64);

        // ---- update epilogue (full-lane, register h/u) ----
        {
            const bool v0 = t < sl0;   // row r0 valid
            const bool v1 = t < sl1;   // row r0+1 valid
            // (row r0, col c0)
            {
                const float xv = (top ? c02 : cc0[0]) + bc0v;
                const float e  = __expf(2.0f * xv);
                const float cd = 1.0f - 2.0f * __builtin_amdgcn_rcpf(e + 1.0f);
                const float nh = fmaf(ug00, cd - h00, h00);
                h00 = v0 ? nh : h00;
                hb[r0 * SB + c0] = f2bf(h00);
                OUT[((long)(b0 + r0) * TT + t) * HH + c0] = v0 ? nh : 0.f;
            }
            // (row r0+1, col c0)
            {
                const float xv = (top ? c03 : cc0[1]) + bc0v;
                const float e  = __expf(2.0f * xv);
                const float cd = 1.0f - 2.0f * __builtin_amdgcn_rcpf(e + 1.0f);
                const float nh = fmaf(ug10, cd - h10, h10);
                h10 = v1 ? nh : h10;
                hb[(r0 + 1) * SB + c0] = f2bf(h10);
                OUT[((long)(b0 + r0 + 1) * TT + t) * HH + c0] = v1 ? nh : 0.f;
            }
            // (row r0, col c1)
            {
                const float xv = (top ? c12 : cc1[0]) + bc1v;
                const float e  = __expf(2.0f * xv);
                const float cd = 1.0f - 2.0f * __builtin_amdgcn_rcpf(e + 1.0f);
                const float nh = fmaf(ug01, cd - h01, h01);
                h01 = v0 ? nh : h01;
                hb[r0 * SB + c1] = f2bf(h01);
                OUT[((long)(b0 + r0) * TT + t) * HH + c1] = v0 ? nh : 0.f;
            }
            // (row r0+1, col c1)
            {
                const float xv = (top ? c13 : cc1[1]) + bc1v;
                const float e  = __expf(2.0f * xv);
                const float cd = 1.0f - 2.0f * __builtin_amdgcn_rcpf(e + 1.0f);
                const float nh = fmaf(ug11, cd - h11, h11);
                h11 = v1 ? nh : h11;
                hb[(r0 + 1) * SB + c1] = f2bf(h11);
                OUT[((long)(b0 + r0 + 1) * TT + t) * HH + c1] = v1 ? nh : 0.f;
            }
        }
        lds_barrier();   // SYNC A for t+1: h (and staged x) ready
    }

    // tail: outputs for t in [tmax, TT) are zeros
    const int n4 = (TT - tmax) * (HH / 4);
    for (int r = 0; r < BM; ++r) {
        float4* p = (float4*)(OUT + ((long)(b0 + r) * TT + tmax) * HH);
        for (int i = tid; i < n4; i += NTH) p[i] = make_float4(0.f, 0.f, 0.f, 0.f);
    }
}

extern "C" void kernel_launch(void* const* d_in, const int* in_sizes, int n_in,
                              void* d_out, int out_size, void* d_ws, size_t ws_size,
                              hipStream_t stream) {
    (void)in_sizes; (void)n_in; (void)d_ws; (void)ws_size; (void)out_size;
    const float* X   = (const float*)d_in[0];
    const float* ATT = (const float*)d_in[1];
    const int*   SL  = (const int*)d_in[2];
    const float* WG  = (const float*)d_in[3];
    const float* BG  = (const float*)d_in[4];
    const float* WC  = (const float*)d_in[5];
    const float* BC  = (const float*)d_in[6];
    float*       OUT = (float*)d_out;
    hipLaunchKernelGGL(augru_kernel, dim3(BB / BM), dim3(NTH), 0, stream,
                       X, ATT, SL, WG, BG, WC, BC, OUT);
}